// Round 2
// baseline (140.824 us; speedup 1.0000x reference)
//
#include <hip/hip_runtime.h>

#define NB  32
#define NLQ 64
#define NLV 128
#define NQS 512
#define NFS 1024
#define NBN 512
#define CC  2.8853900817779268f   // 2*log2(e):  exp(2x) = exp2(CC*x)

typedef float  floatx4 __attribute__((ext_vector_type(4)));
typedef __bf16 bf16x8  __attribute__((ext_vector_type(8)));
typedef unsigned short us;

__device__ __forceinline__ us f2bf(float f) {
    unsigned int u = __float_as_uint(f);
    u += 0x7fffu + ((u >> 16) & 1u);   // round-to-nearest-even
    return (us)(u >> 16);
}
// truncating pack of two fp32 -> packed bf16x2, one v_perm_b32
__device__ __forceinline__ unsigned int pktrunc(float lo, float hi) {
    return __builtin_amdgcn_perm(__float_as_uint(hi), __float_as_uint(lo), 0x07060302u);
}
__device__ __forceinline__ float blo(unsigned int u) {
    return __uint_as_float(u << 16);
}
__device__ __forceinline__ float bhi(unsigned int u) {
    return __uint_as_float(u & 0xffff0000u);
}

// ---------------- GEMM: 64x64 tile, K-tile 32, fp32 in (cvt in-reg), 4 waves
// Epilogue: Y = exp2(CC*(acc[+bias])) stored bf16 (tanh product trick).
// Side-writes (by==0 blocks only):
//   sgf  != null -> store fp32 A tile rows into out_sgf[:, 0:512] (concat left)
//   visb != null -> store bf16-packed A tile into vis_b (reused by attn phase 3)
__device__ __forceinline__ void gemm64(
    us* As, us* Bs,                       // [64*40] each
    const float* __restrict__ A, const float* __restrict__ Bt,
    const float* __restrict__ bias, us* __restrict__ C,
    int K, int bx, int by, int hasb,
    float* __restrict__ sgf, us* __restrict__ visb)
{
    const int tid  = threadIdx.x;
    const int m0   = bx * 64;
    const int n0   = by * 64;
    const int wave = tid >> 6;
    const int lane = tid & 63;
    const int wm   = (wave >> 1) * 32;
    const int wn   = (wave & 1) * 32;
    const int srow = tid >> 2;          // 0..63
    const int sk   = (tid & 3) * 8;     // k offset (elements): 0,8,16,24
    const int fm   = lane & 15;
    const int fko  = (lane >> 4) * 8;

    floatx4 acc[2][2] = {};
    const float* ag = A  + (size_t)(m0 + srow) * K + sk;
    const float* bg = Bt + (size_t)(n0 + srow) * K + sk;

    float4 a0 = *(const float4*)(ag),     a1 = *(const float4*)(ag + 4);
    float4 b0 = *(const float4*)(bg),     b1 = *(const float4*)(bg + 4);

    for (int k0 = 0; k0 < K; k0 += 32) {
        __syncthreads();
        if (sgf) {          // concat left half: fp32, exact
            float* d = sgf + (size_t)(m0 + srow) * (NQS + NFS) + k0 + sk;
            *(float4*)d       = a0;
            *(float4*)(d + 4) = a1;
        }
        uint4 av = { pktrunc(a0.x, a0.y), pktrunc(a0.z, a0.w),
                     pktrunc(a1.x, a1.y), pktrunc(a1.z, a1.w) };
        uint4 bv = { pktrunc(b0.x, b0.y), pktrunc(b0.z, b0.w),
                     pktrunc(b1.x, b1.y), pktrunc(b1.z, b1.w) };
        if (visb)           // bf16 vis copy for attn phase 3
            *(uint4*)(visb + (size_t)(m0 + srow) * NFS + k0 + sk) = av;
        *(uint4*)(As + srow * 40 + sk) = av;
        *(uint4*)(Bs + srow * 40 + sk) = bv;
        const int kn = k0 + 32;
        if (kn < K) {                   // next-tile load; hidden by other blocks
            a0 = *(const float4*)(ag + kn); a1 = *(const float4*)(ag + kn + 4);
            b0 = *(const float4*)(bg + kn); b1 = *(const float4*)(bg + kn + 4);
        }
        __syncthreads();
        bf16x8 am[2], bn[2];
        #pragma unroll
        for (int i = 0; i < 2; ++i)
            am[i] = *(const bf16x8*)(As + (wm + 16 * i + fm) * 40 + fko);
        #pragma unroll
        for (int j = 0; j < 2; ++j)
            bn[j] = *(const bf16x8*)(Bs + (wn + 16 * j + fm) * 40 + fko);
        #pragma unroll
        for (int i = 0; i < 2; ++i)
            #pragma unroll
            for (int j = 0; j < 2; ++j)
                acc[i][j] = __builtin_amdgcn_mfma_f32_16x16x32_bf16(am[i], bn[j], acc[i][j], 0, 0, 0);
    }

    // C/D layout: col = lane&15, row = (lane>>4)*4 + reg
    const int cr = (lane >> 4) * 4;
    const int cc = lane & 15;
    #pragma unroll
    for (int i = 0; i < 2; ++i)
        #pragma unroll
        for (int j = 0; j < 2; ++j)
            #pragma unroll
            for (int r = 0; r < 4; ++r) {
                int gm = m0 + wm + 16 * i + cr + r;
                int gn = n0 + wn + 16 * j + cc;
                float v = acc[i][j][r];
                if (hasb) v += bias[gn];
                C[(size_t)gm * NBN + gn] = f2bf(__builtin_amdgcn_exp2f(CC * v));
            }
}

// blocks 0..255: Yq=exp2(CC*(phr@W^T+b)) (M=2048,K=512, nbx=32)
// blocks 256..767: Yv=exp2(CC*(vis@U^T)) (M=4096,K=1024, nbx=64)
// bx = blk % nbx with 8|nbx -> blocks sharing A-rows land on one XCD's L2
__global__ __launch_bounds__(256) void gemm_both(
    const float* __restrict__ phr, const float* __restrict__ W,
    const float* __restrict__ bias,
    const float* __restrict__ vis, const float* __restrict__ U,
    us* __restrict__ whY, us* __restrict__ uvY,
    float* __restrict__ out_sgf, us* __restrict__ vis_b)
{
    __shared__ __align__(16) us As[64 * 40];
    __shared__ __align__(16) us Bs[64 * 40];
    int blk = blockIdx.x;
    if (blk < 256) {
        int bx = blk % 32, by = blk / 32;
        gemm64(As, Bs, phr, W, bias, whY, NQS, bx, by, 1,
               by == 0 ? out_sgf : nullptr, nullptr);
    } else {
        blk -= 256;
        int bx = blk % 64, by = blk / 64;
        gemm64(As, Bs, vis, U, bias, uvY, NFS, bx, by, 0,
               nullptr, by == 0 ? vis_b : nullptr);
    }
}

// ---------------- fused energies + softmax + aligned -----------------------
// blk = qg*32 + b. 512 threads (8 waves), 4 q per block.
// Phase 1: e[4][128]; each wave 16 v rows; Yv load+unpack amortized over 4 q.
// Phase 2: waves 0-3 softmax (q=wave).
// Phase 3: aligned: thread owns 2 f x 4 q; p from LDS (broadcast), vis bf16.
__global__ __launch_bounds__(512, 4) void attn_fused(
    const us* __restrict__ whY,       // [2048,512] bf16
    const us* __restrict__ uvY,       // [4096,512] bf16
    const float* __restrict__ wvec,
    const us* __restrict__ vis_b,     // [32,128,1024] bf16 (from gemm side-write)
    float* __restrict__ out_sgf, float* __restrict__ out_w, float* __restrict__ out_e)
{
    const float LOG2E = 1.4426950408889634f;
    const int blk  = blockIdx.x;
    const int b    = blk & 31;
    const int qg   = blk >> 5;        // 0..15
    const int tid  = threadIdx.x;
    const int wave = tid >> 6;        // 0..7
    const int lane = tid & 63;

    __shared__ float e_s[4][128];
    __shared__ float p_s[4][128];

    // ---- Phase 1: energies ----
    const int n0 = lane << 3;
    float Yq[4][8];
    #pragma unroll
    for (int qq = 0; qq < 4; ++qq) {
        uint4 y = *(const uint4*)(whY + (size_t)(b * NLQ + qg * 4 + qq) * NBN + n0);
        Yq[qq][0] = blo(y.x); Yq[qq][1] = bhi(y.x);
        Yq[qq][2] = blo(y.y); Yq[qq][3] = bhi(y.y);
        Yq[qq][4] = blo(y.z); Yq[qq][5] = bhi(y.z);
        Yq[qq][6] = blo(y.w); Yq[qq][7] = bhi(y.w);
    }
    float4 w0 = *(const float4*)(wvec + n0);
    float4 w1 = *(const float4*)(wvec + n0 + 4);
    float nw2[8] = { 2.f*w0.x, 2.f*w0.y, 2.f*w0.z, 2.f*w0.w,
                     2.f*w1.x, 2.f*w1.y, 2.f*w1.z, 2.f*w1.w };
    float sumw = w0.x + w0.y + w0.z + w0.w + w1.x + w1.y + w1.z + w1.w;
    #pragma unroll
    for (int off = 32; off; off >>= 1) sumw += __shfl_xor(sumw, off);

    #pragma unroll
    for (int vblk = 0; vblk < 2; ++vblk) {
        const us* base = uvY + ((size_t)b * NLV + wave * 16 + vblk * 8) * NBN + n0;
        float s[4][8];
        #pragma unroll
        for (int j = 0; j < 8; ++j) {
            uint4 u = *(const uint4*)(base + (size_t)j * NBN);
            float yv[8] = { blo(u.x), bhi(u.x), blo(u.y), bhi(u.y),
                            blo(u.z), bhi(u.z), blo(u.w), bhi(u.w) };
            #pragma unroll
            for (int qq = 0; qq < 4; ++qq) {
                float a = 0.f;
                #pragma unroll
                for (int k = 0; k < 8; ++k) {
                    float d = fmaf(yv[k], Yq[qq][k], 1.f);
                    a = fmaf(nw2[k], __builtin_amdgcn_rcpf(d), a);
                }
                s[qq][j] = a;
            }
        }
        #pragma unroll
        for (int qq = 0; qq < 4; ++qq) {
            // uniform reduce over lane-bits 3,4,5 (ILP across 8 accumulators)
            #pragma unroll
            for (int m = 8; m <= 32; m <<= 1)
                #pragma unroll
                for (int j = 0; j < 8; ++j) s[qq][j] += __shfl_xor(s[qq][j], m);
            // reduce-scatter over lane-bits 0,1,2
            float t[4];
            #pragma unroll
            for (int p = 0; p < 4; ++p) {
                float ae = s[qq][2*p]     + __shfl_xor(s[qq][2*p],     1);
                float bo = s[qq][2*p + 1] + __shfl_xor(s[qq][2*p + 1], 1);
                t[p] = (lane & 1) ? bo : ae;
            }
            float u2[2];
            #pragma unroll
            for (int p = 0; p < 2; ++p) {
                float ae = t[2*p]     + __shfl_xor(t[2*p],     2);
                float bo = t[2*p + 1] + __shfl_xor(t[2*p + 1], 2);
                u2[p] = (lane & 2) ? bo : ae;
            }
            float ae = u2[0] + __shfl_xor(u2[0], 4);
            float bo = u2[1] + __shfl_xor(u2[1], 4);
            float r  = (lane & 4) ? bo : ae;
            if (lane < 8) e_s[qq][wave * 16 + vblk * 8 + lane] = sumw - r;
        }
    }
    __syncthreads();

    // ---- Phase 2: softmax (waves 0-3) ----
    if (wave < 4) {
        const int q = wave;
        float e0 = e_s[q][lane];
        float e1 = e_s[q][lane + 64];
        float m = fmaxf(e0, e1);
        #pragma unroll
        for (int off = 32; off; off >>= 1) m = fmaxf(m, __shfl_xor(m, off));
        float x0 = __builtin_amdgcn_exp2f((e0 - m) * LOG2E);
        float x1 = __builtin_amdgcn_exp2f((e1 - m) * LOG2E);
        float ss = x0 + x1;
        #pragma unroll
        for (int off = 32; off; off >>= 1) ss += __shfl_xor(ss, off);
        float inv = __builtin_amdgcn_rcpf(ss);
        float p0 = x0 * inv, p1 = x1 * inv;
        size_t o = (size_t)(b * NLQ + qg * 4 + q) * NLV;
        out_w[o + lane]      = p0;
        out_w[o + lane + 64] = p1;
        out_e[o + lane]      = e0;
        out_e[o + lane + 64] = e1;
        p_s[q][lane]      = p0;
        p_s[q][lane + 64] = p1;
    }
    __syncthreads();

    // ---- Phase 3: aligned (bf16 vis from gemm side-write) ----
    const int f0 = tid << 1;          // 512 threads x 2 f = 1024
    float2 acc[4] = {};
    const us* vb = vis_b + (size_t)b * NLV * NFS + f0;
    for (int v0 = 0; v0 < NLV; v0 += 4) {
        float4 pv[4];
        #pragma unroll
        for (int qq = 0; qq < 4; ++qq) pv[qq] = *(const float4*)&p_s[qq][v0];
        #pragma unroll
        for (int dv = 0; dv < 4; ++dv) {
            unsigned int u = *(const unsigned int*)(vb + (size_t)(v0 + dv) * NFS);
            float x0 = blo(u), x1 = bhi(u);
            #pragma unroll
            for (int qq = 0; qq < 4; ++qq) {
                float p = (dv == 0) ? pv[qq].x : (dv == 1) ? pv[qq].y
                        : (dv == 2) ? pv[qq].z : pv[qq].w;
                acc[qq].x = fmaf(p, x0, acc[qq].x);
                acc[qq].y = fmaf(p, x1, acc[qq].y);
            }
        }
    }
    #pragma unroll
    for (int qq = 0; qq < 4; ++qq) {
        size_t row = (size_t)(b * NLQ + qg * 4 + qq);
        *(float2*)(out_sgf + row * (NQS + NFS) + NQS + f0) = acc[qq];
    }
}

extern "C" void kernel_launch(void* const* d_in, const int* in_sizes, int n_in,
                              void* d_out, int out_size, void* d_ws, size_t ws_size,
                              hipStream_t stream) {
    const float* phr  = (const float*)d_in[0];
    const float* vis  = (const float*)d_in[1];
    const float* W    = (const float*)d_in[2];
    const float* U    = (const float*)d_in[3];
    const float* bias = (const float*)d_in[4];
    const float* wvec = (const float*)d_in[5];

    char* ws = (char*)d_ws;
    us* whY   = (us*)ws;                   // 2 MB  [2048,512] bf16
    us* uvY   = (us*)(ws + (2u << 20));    // 4 MB  [4096,512] bf16
    us* vis_b = (us*)(ws + (6u << 20));    // 8 MB  [32,128,1024] bf16

    float* out     = (float*)d_out;
    float* out_sgf = out;
    float* out_w   = out_sgf + (size_t)NB * NLQ * (NQS + NFS);
    float* out_e   = out_w   + (size_t)NB * NLQ * NLV;

    gemm_both<<<768, 256, 0, stream>>>(phr, W, bias, vis, U, whY, uvY,
                                       out_sgf, vis_b);
    attn_fused<<<NB * 16, 512, 0, stream>>>(whY, uvY, wvec, vis_b,
                                            out_sgf, out_w, out_e);
}

// Round 3
// 128.181 us; speedup vs baseline: 1.0986x; 1.0986x over previous
//
#include <hip/hip_runtime.h>

#define NB  32
#define NLQ 64
#define NLV 128
#define NQS 512
#define NFS 1024
#define NBN 512
#define CC  2.8853900817779268f   // 2*log2(e):  exp(2x) = exp2(CC*x)

typedef float  floatx4 __attribute__((ext_vector_type(4)));
typedef __bf16 bf16x8  __attribute__((ext_vector_type(8)));
typedef unsigned short us;

__device__ __forceinline__ us f2bf(float f) {
    unsigned int u = __float_as_uint(f);
    u += 0x7fffu + ((u >> 16) & 1u);   // round-to-nearest-even
    return (us)(u >> 16);
}
// truncating pack of two fp32 -> packed bf16x2, one v_perm_b32
__device__ __forceinline__ unsigned int pktrunc(float lo, float hi) {
    return __builtin_amdgcn_perm(__float_as_uint(hi), __float_as_uint(lo), 0x07060302u);
}
__device__ __forceinline__ float blo(unsigned int u) {
    return __uint_as_float(u << 16);
}
__device__ __forceinline__ float bhi(unsigned int u) {
    return __uint_as_float(u & 0xffff0000u);
}

// ---------------- GEMM: 64x64 tile, K-tile 32, fp32 in (cvt in-reg), 4 waves
// mode Yq (whYp != null): C = exp2(CC*(acc+bias)) stored FP32 to whY[2048][512]
//   by==0 blocks also copy fp32 A rows into out_sgf[:, 0:512].
// mode Yv (uvYTp != null): C = exp2(CC*acc) stored bf16 TRANSPOSED to
//   uvYT[b][n][v]; by==0 blocks also write the staged A tile transposed
//   (bf16) to visbT[b][f][v] for the aligned MFMA kernel.
__device__ __forceinline__ void gemm64(
    us* As, us* Bs,                       // [64*40] each
    const float* __restrict__ A, const float* __restrict__ Bt,
    const float* __restrict__ bias,
    float* __restrict__ whYp, us* __restrict__ uvYTp,
    int K, int bx, int by,
    float* __restrict__ sgf, us* __restrict__ visbT)
{
    const int tid  = threadIdx.x;
    const int m0   = bx * 64;
    const int n0   = by * 64;
    const int wave = tid >> 6;
    const int lane = tid & 63;
    const int wm   = (wave >> 1) * 32;
    const int wn   = (wave & 1) * 32;
    const int srow = tid >> 2;          // 0..63
    const int sk   = (tid & 3) * 8;     // k offset (elements): 0,8,16,24
    const int fm   = lane & 15;
    const int fko  = (lane >> 4) * 8;

    floatx4 acc[2][2] = {};
    const float* ag = A  + (size_t)(m0 + srow) * K + sk;
    const float* bg = Bt + (size_t)(n0 + srow) * K + sk;

    float4 a0 = *(const float4*)(ag),     a1 = *(const float4*)(ag + 4);
    float4 b0 = *(const float4*)(bg),     b1 = *(const float4*)(bg + 4);

    for (int k0 = 0; k0 < K; k0 += 32) {
        __syncthreads();
        if (sgf) {          // concat left half: fp32, exact
            float* d = sgf + (size_t)(m0 + srow) * (NQS + NFS) + k0 + sk;
            *(float4*)d       = a0;
            *(float4*)(d + 4) = a1;
        }
        uint4 av = { pktrunc(a0.x, a0.y), pktrunc(a0.z, a0.w),
                     pktrunc(a1.x, a1.y), pktrunc(a1.z, a1.w) };
        uint4 bv = { pktrunc(b0.x, b0.y), pktrunc(b0.z, b0.w),
                     pktrunc(b1.x, b1.y), pktrunc(b1.z, b1.w) };
        *(uint4*)(As + srow * 40 + sk) = av;
        *(uint4*)(Bs + srow * 40 + sk) = bv;
        const int kn = k0 + 32;
        if (kn < K) {                   // next-tile load; hidden by other blocks
            a0 = *(const float4*)(ag + kn); a1 = *(const float4*)(ag + kn + 4);
            b0 = *(const float4*)(bg + kn); b1 = *(const float4*)(bg + kn + 4);
        }
        __syncthreads();
        bf16x8 am[2], bn[2];
        #pragma unroll
        for (int i = 0; i < 2; ++i)
            am[i] = *(const bf16x8*)(As + (wm + 16 * i + fm) * 40 + fko);
        #pragma unroll
        for (int j = 0; j < 2; ++j)
            bn[j] = *(const bf16x8*)(Bs + (wn + 16 * j + fm) * 40 + fko);
        #pragma unroll
        for (int i = 0; i < 2; ++i)
            #pragma unroll
            for (int j = 0; j < 2; ++j)
                acc[i][j] = __builtin_amdgcn_mfma_f32_16x16x32_bf16(am[i], bn[j], acc[i][j], 0, 0, 0);

        if (visbT) {        // transposed bf16 vis tile: visbT[b][f][v]
            const int bb = m0 >> 7, vbase = m0 & 127;
            #pragma unroll
            for (int h = 0; h < 2; ++h) {
                int idx = h * 256 + tid;       // 0..511 -> (f, v-quad)
                int f   = idx >> 4;            // 0..31
                int v0  = (idx & 15) * 4;
                us e0 = As[(v0 + 0) * 40 + f];
                us e1 = As[(v0 + 1) * 40 + f];
                us e2 = As[(v0 + 2) * 40 + f];
                us e3 = As[(v0 + 3) * 40 + f];
                uint2 pk2 = { (unsigned int)e0 | ((unsigned int)e1 << 16),
                              (unsigned int)e2 | ((unsigned int)e3 << 16) };
                *(uint2*)(visbT + ((size_t)bb * NFS + k0 + f) * NLV + vbase + v0) = pk2;
            }
        }
    }

    // C/D layout: col = lane&15, row = (lane>>4)*4 + reg
    const int cr = (lane >> 4) * 4;
    const int cc = lane & 15;
    if (whYp) {
        #pragma unroll
        for (int i = 0; i < 2; ++i)
            #pragma unroll
            for (int j = 0; j < 2; ++j)
                #pragma unroll
                for (int r = 0; r < 4; ++r) {
                    int gm = m0 + wm + 16 * i + cr + r;
                    int gn = n0 + wn + 16 * j + cc;
                    float v = acc[i][j][r] + bias[gn];
                    whYp[(size_t)gm * NBN + gn] = __builtin_amdgcn_exp2f(CC * v);
                }
    } else {
        #pragma unroll
        for (int i = 0; i < 2; ++i)
            #pragma unroll
            for (int j = 0; j < 2; ++j) {
                int gm0 = m0 + wm + 16 * i + cr;       // v-run base (4 rows)
                int gn  = n0 + wn + 16 * j + cc;       // n
                int bb  = gm0 >> 7, v = gm0 & 127;
                unsigned int y0 = f2bf(__builtin_amdgcn_exp2f(CC * acc[i][j][0]));
                unsigned int y1 = f2bf(__builtin_amdgcn_exp2f(CC * acc[i][j][1]));
                unsigned int y2 = f2bf(__builtin_amdgcn_exp2f(CC * acc[i][j][2]));
                unsigned int y3 = f2bf(__builtin_amdgcn_exp2f(CC * acc[i][j][3]));
                uint2 pk2 = { y0 | (y1 << 16), y2 | (y3 << 16) };
                *(uint2*)(uvYTp + ((size_t)bb * NBN + gn) * NLV + v) = pk2;
            }
    }
}

// blocks 0..255: Yq (M=2048,K=512, nbx=32); 256..767: Yv (M=4096,K=1024, nbx=64)
__global__ __launch_bounds__(256) void gemm_both(
    const float* __restrict__ phr, const float* __restrict__ W,
    const float* __restrict__ bias,
    const float* __restrict__ vis, const float* __restrict__ U,
    float* __restrict__ whY, us* __restrict__ uvYT,
    float* __restrict__ out_sgf, us* __restrict__ visbT)
{
    __shared__ __align__(16) us As[64 * 40];
    __shared__ __align__(16) us Bs[64 * 40];
    int blk = blockIdx.x;
    if (blk < 256) {
        int bx = blk % 32, by = blk / 32;
        gemm64(As, Bs, phr, W, bias, whY, nullptr, NQS, bx, by,
               by == 0 ? out_sgf : nullptr, nullptr);
    } else {
        blk -= 256;
        int bx = blk % 64, by = blk / 64;
        gemm64(As, Bs, vis, U, bias, nullptr, uvYT, NFS, bx, by,
               nullptr, by == 0 ? visbT : nullptr);
    }
}

// ---------------- energize: in-thread n-reduction, zero shuffle-reduce ------
// block = (b, q-quad), 4 waves = n-quarters. lane owns v-pair (2*lane, 2*lane+1).
// Yq (fp32) and w are wave-uniform -> scalar loads; Yv from transposed uvYT.
// e[q][v] accumulates fully in VGPRs; one tiny LDS combine + softmax at end.
__global__ __launch_bounds__(256) void energize(
    const float* __restrict__ whY,    // [2048][512] fp32 = exp(2(Wh+b))
    const us* __restrict__ uvYT,      // [32][512][128] bf16 = exp(2Uv), [n][v]
    const float* __restrict__ wvec,   // [512]
    float* __restrict__ out_w, float* __restrict__ out_e,
    us* __restrict__ p_bf, us* __restrict__ p_lo)   // [2048][128]
{
    const float LOG2E = 1.4426950408889634f;
    int blk = blockIdx.x;
    blk = (blk & 7) * 64 + (blk >> 3);    // bijective XCD swizzle (512 = 8*64)
    const int b    = blk >> 4;            // b-major: 16 blocks share uvYT[b]
    const int qq4  = blk & 15;
    const int tid  = threadIdx.x;
    const int wave = __builtin_amdgcn_readfirstlane(tid >> 6);  // n-quarter
    const int lane = tid & 63;
    const int q0   = qq4 * 4;

    __shared__ float part[4][4][NLV];     // [q][nq][v]

    // sumw (once per wave)
    float4 sw0 = *(const float4*)(wvec + lane * 8);
    float4 sw1 = *(const float4*)(wvec + lane * 8 + 4);
    float sumw = sw0.x + sw0.y + sw0.z + sw0.w + sw1.x + sw1.y + sw1.z + sw1.w;
    #pragma unroll
    for (int off = 32; off; off >>= 1) sumw += __shfl_xor(sumw, off);

    const float* yqp = whY + (size_t)(b * NLQ + q0) * NBN + wave * 128;
    const float* wp  = wvec + wave * 128;
    const us*    uvp = uvYT + ((size_t)b * NBN + wave * 128) * NLV + 2 * lane;

    float acc[4][2] = {};
    #pragma unroll 2
    for (int nc = 0; nc < 128; nc += 8) {
        unsigned int yv[8];
        #pragma unroll
        for (int k = 0; k < 8; ++k)
            yv[k] = *(const unsigned int*)(uvp + (size_t)(nc + k) * NLV);
        #pragma unroll
        for (int k = 0; k < 8; ++k) {
            float x0 = blo(yv[k]), x1 = bhi(yv[k]);
            float wk = wp[nc + k];                      // uniform -> SGPR
            #pragma unroll
            for (int q = 0; q < 4; ++q) {
                float yq = yqp[q * NBN + nc + k];       // uniform -> SGPR
                float d0 = fmaf(x0, yq, 1.f);
                float d1 = fmaf(x1, yq, 1.f);
                acc[q][0] = fmaf(wk, __builtin_amdgcn_rcpf(d0), acc[q][0]);
                acc[q][1] = fmaf(wk, __builtin_amdgcn_rcpf(d1), acc[q][1]);
            }
        }
    }
    #pragma unroll
    for (int q = 0; q < 4; ++q) {
        float2 t = { acc[q][0], acc[q][1] };
        *(float2*)&part[q][wave][2 * lane] = t;
    }
    __syncthreads();

    // softmax: wave w handles q = w (exactly 4 q, 4 waves)
    const int q = wave;
    float s0 = 0.f, s1 = 0.f;
    #pragma unroll
    for (int nq = 0; nq < 4; ++nq) {
        s0 += part[q][nq][2 * lane];
        s1 += part[q][nq][2 * lane + 1];
    }
    float e0 = sumw - 2.f * s0;
    float e1 = sumw - 2.f * s1;
    float m = fmaxf(e0, e1);
    #pragma unroll
    for (int off = 32; off; off >>= 1) m = fmaxf(m, __shfl_xor(m, off));
    float x0 = __builtin_amdgcn_exp2f((e0 - m) * LOG2E);
    float x1 = __builtin_amdgcn_exp2f((e1 - m) * LOG2E);
    float ss = x0 + x1;
    #pragma unroll
    for (int off = 32; off; off >>= 1) ss += __shfl_xor(ss, off);
    float inv = __builtin_amdgcn_rcpf(ss);
    float p0 = x0 * inv, p1 = x1 * inv;

    const size_t row = (size_t)(b * NLQ + q0 + q);
    float2 ep = { e0, e1 };
    float2 pp = { p0, p1 };
    *(float2*)(out_e + row * NLV + 2 * lane) = ep;
    *(float2*)(out_w + row * NLV + 2 * lane) = pp;
    // bf16 p + bf16 correction (restores fp32 accuracy in the MFMA)
    unsigned int pb0 = f2bf(p0), pb1 = f2bf(p1);
    float lo0 = p0 - __uint_as_float(pb0 << 16);
    float lo1 = p1 - __uint_as_float(pb1 << 16);
    unsigned int lb0 = f2bf(lo0), lb1 = f2bf(lo1);
    *(unsigned int*)(p_bf + row * NLV + 2 * lane) = pb0 | (pb1 << 16);
    *(unsigned int*)(p_lo + row * NLV + 2 * lane) = lb0 | (lb1 << 16);
}

// ---------------- aligned via MFMA: out = (P + P_lo) . V ---------------------
// block = (b, f-tile of 64), 4 waves, each a 32q x 32f quadrant. Fragments load
// directly from L2 (16B/lane contiguous); no LDS, no barriers.
__global__ __launch_bounds__(256) void aligned_mfma(
    const us* __restrict__ p_bf, const us* __restrict__ p_lo,  // [2048][128]
    const us* __restrict__ visbT,                              // [32][1024][128]
    float* __restrict__ out_sgf)
{
    int blk = blockIdx.x;
    blk = (blk & 7) * 64 + (blk >> 3);    // XCD swizzle, b-major
    const int b    = blk >> 4;
    const int ft   = blk & 15;
    const int tid  = threadIdx.x;
    const int wave = tid >> 6;
    const int lane = tid & 63;
    const int wm   = (wave >> 1) * 32;    // q offset
    const int wf   = (wave & 1) * 32;     // f offset
    const int fm   = lane & 15;
    const int fko  = (lane >> 4) * 8;

    floatx4 acc[2][2] = {};
    const us* pA  = p_bf + ((size_t)b * NLQ + wm + fm) * NLV + fko;
    const us* pAl = p_lo + ((size_t)b * NLQ + wm + fm) * NLV + fko;
    const us* pB  = visbT + ((size_t)b * NFS + ft * 64 + wf + fm) * NLV + fko;

    #pragma unroll
    for (int ks = 0; ks < 4; ++ks) {
        bf16x8 a[2], al[2], bb[2];
        #pragma unroll
        for (int i = 0; i < 2; ++i) {
            a[i]  = *(const bf16x8*)(pA  + (size_t)i * 16 * NLV + ks * 32);
            al[i] = *(const bf16x8*)(pAl + (size_t)i * 16 * NLV + ks * 32);
        }
        #pragma unroll
        for (int j = 0; j < 2; ++j)
            bb[j] = *(const bf16x8*)(pB + (size_t)j * 16 * NLV + ks * 32);
        #pragma unroll
        for (int i = 0; i < 2; ++i)
            #pragma unroll
            for (int j = 0; j < 2; ++j) {
                acc[i][j] = __builtin_amdgcn_mfma_f32_16x16x32_bf16(a[i],  bb[j], acc[i][j], 0, 0, 0);
                acc[i][j] = __builtin_amdgcn_mfma_f32_16x16x32_bf16(al[i], bb[j], acc[i][j], 0, 0, 0);
            }
    }

    const int cr = (lane >> 4) * 4;
    const int cc = lane & 15;
    #pragma unroll
    for (int i = 0; i < 2; ++i)
        #pragma unroll
        for (int j = 0; j < 2; ++j)
            #pragma unroll
            for (int r = 0; r < 4; ++r) {
                int q = wm + 16 * i + cr + r;
                int f = ft * 64 + wf + 16 * j + cc;
                size_t row = (size_t)b * NLQ + q;
                out_sgf[row * (NQS + NFS) + NQS + f] = acc[i][j][r];
            }
}

extern "C" void kernel_launch(void* const* d_in, const int* in_sizes, int n_in,
                              void* d_out, int out_size, void* d_ws, size_t ws_size,
                              hipStream_t stream) {
    const float* phr  = (const float*)d_in[0];
    const float* vis  = (const float*)d_in[1];
    const float* W    = (const float*)d_in[2];
    const float* U    = (const float*)d_in[3];
    const float* bias = (const float*)d_in[4];
    const float* wvec = (const float*)d_in[5];

    char* ws = (char*)d_ws;
    float* whY  = (float*)ws;                     // 4 MB [2048][512] fp32
    us* uvYT    = (us*)(ws + (4u << 20));         // 4 MB [32][512][128] bf16
    us* visbT   = (us*)(ws + (8u << 20));         // 8 MB [32][1024][128] bf16
    us* p_bf    = (us*)(ws + (16u << 20));        // 512 KB [2048][128]
    us* p_lo    = (us*)(ws + (16u << 20) + (512u << 10));   // 512 KB

    float* out     = (float*)d_out;
    float* out_sgf = out;
    float* out_w   = out_sgf + (size_t)NB * NLQ * (NQS + NFS);
    float* out_e   = out_w   + (size_t)NB * NLQ * NLV;

    gemm_both<<<768, 256, 0, stream>>>(phr, W, bias, vis, U,
                                       whY, uvYT, out_sgf, visbT);
    energize<<<512, 256, 0, stream>>>(whY, uvYT, wvec, out_w, out_e, p_bf, p_lo);
    aligned_mfma<<<512, 256, 0, stream>>>(p_bf, p_lo, visbT, out_sgf);
}